// Round 3
// baseline (251.147 us; speedup 1.0000x reference)
//
#include <hip/hip_runtime.h>
#include <cstdint>

#define K_SEL 4768
#define CAND_CAP 16384
#define NBIN 4096
#define BUFCAP 512
#define TPAD 9216   // padded-triangular T words per (img,lvl): 64 * sum((c+1)|1, c=0..15)

struct P5 { const float* p[5]; };

__device__ __forceinline__ unsigned fsortkey(float f) {
  unsigned b = __float_as_uint(f);
  return (b & 0x80000000u) ? ~b : (b | 0x80000000u);
}

// ------- histogram of sortable-logit top-12 bits per (img,lvl): per-block partials ------
__global__ __launch_bounds__(256) void k_hist(P5 obj, unsigned* phist) {
  int p = blockIdx.y; int img = p / 5, lvl = p % 5;
  int f = 256 >> lvl; int n = 3 * f * f;
  __shared__ unsigned lh[NBIN];
  for (int b = threadIdx.x; b < NBIN; b += 256) lh[b] = 0;
  __syncthreads();
  const float4* src4 = (const float4*)(obj.p[lvl] + (size_t)img * n);
  int n4 = n >> 2;
  int chunk = (n4 + gridDim.x - 1) / gridDim.x;
  int e0 = blockIdx.x * chunk, e1 = min(n4, e0 + chunk);
  for (int e = e0 + threadIdx.x; e < e1; e += 256) {
    float4 v = src4[e];
    atomicAdd(&lh[fsortkey(v.x) >> 20], 1u);
    atomicAdd(&lh[fsortkey(v.y) >> 20], 1u);
    atomicAdd(&lh[fsortkey(v.z) >> 20], 1u);
    atomicAdd(&lh[fsortkey(v.w) >> 20], 1u);
  }
  __syncthreads();
  unsigned* dst = phist + ((size_t)(p * 8 + blockIdx.x)) * NBIN;
  for (int b = threadIdx.x; b < NBIN; b += 256) dst[b] = lh[b];   // unconditional: no pre-zero
}

// ------- sum partials, find threshold bin B (count(bin >= B) >= kk), zero cnt ----------
__global__ __launch_bounds__(256) void k_thresh(const unsigned* phist, int* Bthr, unsigned* cnt) {
  int p = blockIdx.x; int lvl = p % 5;
  unsigned kk = (lvl == 4) ? 768u : 1000u;
  __shared__ unsigned hsum[NBIN];
  __shared__ unsigned csum[256];
  int c = threadIdx.x;
  unsigned tot[16];
#pragma unroll
  for (int k = 0; k < 16; ++k) tot[k] = 0;
  for (int g = 0; g < 8; ++g) {
    const unsigned* hp = phist + ((size_t)(p * 8 + g)) * NBIN + c * 16;
#pragma unroll
    for (int k = 0; k < 16; ++k) tot[k] += hp[k];
  }
  unsigned s = 0;
#pragma unroll
  for (int k = 0; k < 16; ++k) { hsum[c * 16 + k] = tot[k]; s += tot[k]; }
  csum[c] = s;
  __syncthreads();
  if (c == 0) {
    unsigned acc = 0; int B = 0;
    for (int cc = 255; cc >= 0; --cc) {
      if (acc + csum[cc] >= kk) {
        for (int b = 15; b >= 0; --b) {
          acc += hsum[cc * 16 + b];
          if (acc >= kk) { B = cc * 16 + b; break; }
        }
        break;
      }
      acc += csum[cc];
    }
    Bthr[p] = B;
    cnt[p] = 0;                              // replaces ws memset for gather's counter
  }
}

// ------- gather candidates (bin >= B): float4 reads, LDS-buffered, ONE atomic per block -
__global__ __launch_bounds__(256) void k_gather(P5 obj, const int* Bthr, unsigned* cnt,
                                                unsigned long long* ck) {
  int p = blockIdx.y; int img = p / 5, lvl = p % 5;
  int f = 256 >> lvl; int hw = f * f; int n = 3 * hw;
  int B = Bthr[p];
  int shift = 2 * (8 - lvl);
  const float4* src4 = (const float4*)(obj.p[lvl] + (size_t)img * n);
  int n4 = n >> 2;
  unsigned long long* dst = ck + (size_t)p * CAND_CAP;
  int tid = threadIdx.x;
  int lane = tid & 63, wv = tid >> 6;
  __shared__ unsigned long long buf[4][BUFCAP];
  __shared__ unsigned wTot[4];
  __shared__ unsigned blkBase;
  unsigned wc = 0;                             // wave-uniform running count
  for (int e = blockIdx.x * 256 + tid; e < n4; e += gridDim.x * 256) {
    float4 v = src4[e];
    float vv[4] = {v.x, v.y, v.z, v.w};
#pragma unroll
    for (int j = 0; j < 4; ++j) {
      unsigned sv = fsortkey(vv[j]);
      bool pass = (int)(sv >> 20) >= B;
      unsigned long long m = __ballot(pass);
      if (m) {
        if (pass) {
          unsigned pos = wc + (unsigned)__popcll(m & ((1ULL << lane) - 1ULL));
          int ee = e * 4 + j;
          int a = ee >> shift;                 // ee / hw
          int r = ee & (hw - 1);               // ee % hw
          unsigned kidx = (unsigned)(r * 3 + a); // reference flatten order (y*W+x)*A + a
          unsigned long long key = ((unsigned long long)sv << 32) | (0xFFFFFFFFu - kidx);
          if (pos < BUFCAP) buf[wv][pos] = key;
          else {                               // overflow safety (pathological skew only)
            unsigned gp = atomicAdd(&cnt[p], 1u);
            if (gp < CAND_CAP) dst[gp] = key;
          }
        }
        wc += (unsigned)__popcll(m);
      }
    }
  }
  if (lane == 0) wTot[wv] = min(wc, (unsigned)BUFCAP);
  __syncthreads();
  if (tid == 0) {
    unsigned tot = wTot[0] + wTot[1] + wTot[2] + wTot[3];
    blkBase = tot ? atomicAdd(&cnt[p], tot) : 0u;
  }
  __syncthreads();
  unsigned myOff = blkBase;
  for (int x = 0; x < wv; ++x) myOff += wTot[x];
  unsigned wn = wTot[wv];
  for (unsigned j = lane; j < wn; j += 64) {
    unsigned gp = myOff + j;
    if (gp < CAND_CAP) dst[gp] = buf[wv][j];   // coalesced flush
  }
}

// ------- exact top-kk per level by rank counting, LDS-staged keys ----------------------
__global__ __launch_bounds__(256) void k_select(const unsigned* cnt, const unsigned long long* ck,
                                                unsigned* selSV, unsigned* selIdx) {
  int p = blockIdx.y; int img = p / 5, lvl = p % 5;
  int Cc = min((int)cnt[p], CAND_CAP);
  if (blockIdx.x * 256 >= Cc) return;
  int kk = (lvl == 4) ? 768 : 1000;
  int soff = lvl * 1000;
  const unsigned long long* keys = ck + (size_t)p * CAND_CAP;
  __shared__ unsigned long long sk[4096];
  int stage = min(Cc, 4096);
  for (int j = threadIdx.x; j < stage; j += 256) sk[j] = keys[j];
  __syncthreads();
  int c = blockIdx.x * 256 + threadIdx.x;
  if (c >= Cc) return;
  unsigned long long kc = keys[c];
  int rank = 0;
#pragma unroll 8
  for (int j = 0; j < stage; ++j) rank += (sk[j] > kc) ? 1 : 0;
  for (int j = stage; j < Cc; ++j) rank += (keys[j] > kc) ? 1 : 0;
  if (rank < kk) {
    int slot = img * K_SEL + soff + rank;
    selSV[slot]  = (unsigned)(kc >> 32);
    selIdx[slot] = 0xFFFFFFFFu - (unsigned)kc;
  }
}

// ---------------- decode + clip + validity for the 4768 selected per image --------------
__global__ __launch_bounds__(256) void k_decode(P5 del, const float* anchors,
                                                const unsigned* selSV, const unsigned* selIdx,
                                                float* boxP, unsigned long long* keyP) {
  int i = blockIdx.x * 256 + threadIdx.x;
  if (i >= K_SEL) return;
  int img = blockIdx.y;
  int lvl = (i < 4000) ? (i / 1000) : 4;
  int f = 256 >> lvl, hw = f * f;
  const int aoffA[5] = {0, 196608, 245760, 258048, 261120};
  int slot = img * K_SEL + i;
  unsigned k = selIdx[slot];
  unsigned sv = selSV[slot];
  int a = (int)(k % 3u); int r = (int)(k / 3u);
  int y = r >> (8 - lvl); int x = r & (f - 1);
  const float* dp = del.p[lvl] + (size_t)(img * 12 + a * 4) * hw + (size_t)y * f + x;
  float d0 = dp[0], d1 = dp[hw], d2 = dp[2 * hw], d3 = dp[3 * hw];
  const float* ar = anchors + (size_t)(aoffA[lvl] + (int)k) * 4;
  float a0 = ar[0], a1 = ar[1], a2 = ar[2], a3 = ar[3];
  // numpy-faithful, no FMA contraction
  float w = __fsub_rn(a2, a0), h = __fsub_rn(a3, a1);
  float cx = __fadd_rn(a0, __fmul_rn(0.5f, w));
  float cy = __fadd_rn(a1, __fmul_rn(0.5f, h));
  const float CLIP = 4.135166556742356f;     // log(1000/16)
  float dw = fminf(d2, CLIP), dh = fminf(d3, CLIP);
  float pcx = __fadd_rn(__fmul_rn(d0, w), cx);
  float pcy = __fadd_rn(__fmul_rn(d1, h), cy);
  float pw = __fmul_rn(expf(dw), w);
  float ph = __fmul_rn(expf(dh), h);
  float x1 = __fsub_rn(pcx, __fmul_rn(0.5f, pw));
  float y1 = __fsub_rn(pcy, __fmul_rn(0.5f, ph));
  float x2 = __fadd_rn(pcx, __fmul_rn(0.5f, pw));
  float y2 = __fadd_rn(pcy, __fmul_rn(0.5f, ph));
  float x1c = fminf(fmaxf(x1, 0.0f), 1024.0f);
  float y1c = fminf(fmaxf(y1, 0.0f), 1024.0f);
  float x2c = fminf(fmaxf(x2, 0.0f), 1024.0f);
  float y2c = fminf(fmaxf(y2, 0.0f), 1024.0f);
  bool valid = (__fsub_rn(x2c, x1c) >= 1e-3f) && (__fsub_rn(y2c, y1c) >= 1e-3f);
  float* bp = boxP + (size_t)slot * 4;
  bp[0] = x1c; bp[1] = y1c; bp[2] = x2c; bp[3] = y2c;
  unsigned low = 0xFFFFFFFFu - (unsigned)i;   // pos asc tie-break, unique keys
  keyP[slot] = valid ? (((unsigned long long)sv << 32) | low) : (unsigned long long)low;
}

// ---------------- IoU on offset boxes, bitwise matching reference -----------------------
__device__ __forceinline__ bool iou_gt(float rx1, float ry1, float rx2, float ry2, float rar,
                                       float cx1, float cy1, float cx2, float cy2, float car) {
  float ltx = fmaxf(rx1, cx1), lty = fmaxf(ry1, cy1);
  float rbx = fminf(rx2, cx2), rby = fminf(ry2, cy2);
  float wx = fmaxf(__fsub_rn(rbx, ltx), 0.0f);
  float wy = fmaxf(__fsub_rn(rby, lty), 0.0f);
  float inter = __fmul_rn(wx, wy);
  float denom = __fadd_rn(__fsub_rn(__fadd_rn(rar, car), inter), 1e-9f);
  return __fdiv_rn(inter, denom) > 0.7f;
}

// ---- TRANSPOSED suppression mask T[i] = "which j<i suppress i", triangular-packed ------
// Role-swap vs row-major version: ROW boxes staged in LDS, COLUMN box in registers ->
// each thread directly accumulates the suppressor word of its column box; no transpose
// step. IoU is bitwise symmetric (fmax/fmin/fsub/fmul/fadd/fdiv identical both ways).
// Packing: row i (chunk ci=i>>6) holds words w=0..ci at T[64*Pt[ci] + (i&63)*sc + w],
// sc=(ci+1)|1 (odd stride -> <=4-way LDS bank conflict when k_lvlnms reads it).
__global__ __launch_bounds__(64) void k_lvlmask(const float* boxP, unsigned long long* T) {
  int img = blockIdx.y;
  int q = blockIdx.x;                        // 0..621 per image
  int lvl, q2;
  if (q < 544) { lvl = q / 136; q2 = q - lvl * 136; }
  else         { lvl = 4;       q2 = q - 544; }
  int kk = (lvl == 4) ? 768 : 1000;
  int nch = (kk + 63) >> 6;
  int rb = 0;
  while (q2 >= nch - rb) { q2 -= nch - rb; ++rb; }    // upper-tri (rb, cb>=rb)
  int cb = rb + q2;
  int t = threadIdx.x;
  float off = __fmul_rn((float)lvl, 1025.0f);
  const float4* b4 = (const float4*)boxP + (size_t)img * K_SEL + lvl * 1000;
  __shared__ float rx1s[64], ry1s[64], rx2s[64], ry2s[64], rars[64];
  int j = rb * 64 + t;                       // ROW box staged in LDS
  if (j < kk) {
    float4 bb = b4[j];
    float ox1 = __fadd_rn(bb.x, off), oy1 = __fadd_rn(bb.y, off);
    float ox2 = __fadd_rn(bb.z, off), oy2 = __fadd_rn(bb.w, off);
    rx1s[t] = ox1; ry1s[t] = oy1; rx2s[t] = ox2; ry2s[t] = oy2;
    rars[t] = __fmul_rn(__fsub_rn(ox2, ox1), __fsub_rn(oy2, oy1));
  }
  __syncthreads();
  int i = cb * 64 + t;                       // COLUMN box in registers
  if (i >= kk) return;
  float4 bb = b4[i];
  float cx1 = __fadd_rn(bb.x, off), cy1 = __fadd_rn(bb.y, off);
  float cx2 = __fadd_rn(bb.z, off), cy2 = __fadd_rn(bb.w, off);
  float car = __fmul_rn(__fsub_rn(cx2, cx1), __fsub_rn(cy2, cy1));
  int jmaxR = min(64, kk - rb * 64);
  int jend = (rb == cb) ? min(t, jmaxR) : jmaxR;      // diag: only rows jj < t
  unsigned long long bits = 0;
  for (int jj = 0; jj < jend; ++jj) {
    if (iou_gt(rx1s[jj], ry1s[jj], rx2s[jj], ry2s[jj], rars[jj], cx1, cy1, cx2, cy2, car))
      bits |= (1ULL << jj);
  }
  const int Pt[16] = {0, 1, 4, 7, 12, 17, 24, 31, 40, 49, 60, 71, 84, 97, 112, 127};
  int sc = (cb + 1) | 1;
  T[(size_t)(img * 5 + lvl) * TPAD + 64 * Pt[cb] + t * sc + rb] = bits;
}

// ---- per-level greedy NMS as a GLOBAL round-based fixpoint, T staged in LDS ------------
// Box i is kept iff no kept j<i suppresses it. Per round: i in U is KEPT if all its
// suppressors are decided-dead (T[i] & (U|K) == 0); DEAD if some suppressor is kept
// (T[i] & K != 0). Lowest undecided box always resolves -> guaranteed progress; chains
// are short -> ~4-8 rounds. No serial chunk chain, no data-dependent shfl.
__global__ __launch_bounds__(256) void k_lvlnms(const unsigned long long* keyP,
                                                const unsigned long long* Tg_,
                                                unsigned long long* keepw) {
  int p = blockIdx.x; int img = p / 5, lvl = p % 5;
  int kk = (lvl == 4) ? 768 : 1000;
  int tw = (lvl == 4) ? 5376 : TPAD;         // words used (lvl4: chunks 0..11 only)
  int tid = threadIdx.x;
  int lane = tid & 63, wv = tid >> 6;
  __shared__ __align__(16) unsigned long long Ts[TPAD];   // 72 KiB
  __shared__ unsigned long long Us[16], Ks[16];
  const unsigned long long* Tg = Tg_ + (size_t)p * TPAD;
  for (int x = tid; x < (tw >> 1); x += 256)
    ((ulonglong2*)Ts)[x] = ((const ulonglong2*)Tg)[x];    // coalesced 16B staging
  const unsigned long long* kp = keyP + (size_t)img * K_SEL + lvl * 1000;
#pragma unroll
  for (int jb = 0; jb < 4; ++jb) {           // init U = valid set, K = 0 (word = ballot)
    int i = jb * 256 + tid;
    bool valid = (i < kk) && ((kp[min(i, kk - 1)] >> 32) != 0ULL);
    unsigned long long m = __ballot(valid);
    if (lane == 0) { int wi = jb * 4 + wv; Us[wi] = m; Ks[wi] = 0ULL; }
  }
  __syncthreads();
  const int Pt[16] = {0, 1, 4, 7, 12, 17, 24, 31, 40, 49, 60, 71, 84, 97, 112, 127};
  while (true) {
    unsigned long long us[16], ks[16], ku[16], uAny = 0;
#pragma unroll
    for (int w = 0; w < 16; ++w) {           // snapshot sets into registers (broadcast reads)
      us[w] = Us[w]; ks[w] = Ks[w]; ku[w] = us[w] | ks[w]; uAny |= us[w];
    }
    __syncthreads();                         // all snapshots taken before any write
    if (uAny == 0ULL) break;                 // uniform across block
#pragma unroll
    for (int jb = 0; jb < 4; ++jb) {
      int i = jb * 256 + tid;
      bool inU = (i < kk) && ((us[i >> 6] >> (i & 63)) & 1ULL);
      bool kept = false, dead = false;
      if (inU) {
        int ci = i >> 6, il = i & 63;
        int base = 64 * Pt[ci] + il * ((ci + 1) | 1);
        unsigned long long a = 0, b = 0;
        for (int w = 0; w <= ci; ++w) {
          unsigned long long tv = Ts[base + w];
          a |= tv & ku[w]; b |= tv & ks[w];
        }
        kept = (a == 0ULL);                  // every suppressor decided-dead
        dead = !kept && (b != 0ULL);         // some suppressor kept
      }
      unsigned long long mk = __ballot(kept), md = __ballot(dead);
      if (lane == 0) {
        int wi = jb * 4 + wv;                // word indices disjoint across (jb,wave)
        Ks[wi] |= mk;
        Us[wi] &= ~(mk | md);
      }
    }
    __syncthreads();
  }
  if (tid < 16) keepw[(size_t)p * 16 + tid] = Ks[tid];
}

// ---- merge: exact global rank of each kept box via per-level compaction + 4 binary
// ---- searches. 40 blocks = (img,lvl): each block compacts ALL levels (cheap, coalesced)
// ---- but ranks only its own level's kept entries -> 5x less serial LDS-chain latency.
// ---- granks biject onto 0..KT-1 so cross-block writes never collide; pad is disjoint.
__global__ __launch_bounds__(256) void k_merge(const unsigned long long* keyP, const float* boxP,
                                               const unsigned long long* keepw, float* out) {
  int p = blockIdx.x; int img = p / 5, lvl = p % 5;
  int tid = threadIdx.x;
  __shared__ unsigned long long lkey[5000];   // level l at l*1000: compacted kept keys (desc)
  __shared__ int lpos[5000];                  // original within-image slot
  __shared__ int wp[5][17];                   // per-level word-prefix popcounts
  __shared__ unsigned long long kwS[80];
  for (int x = tid; x < 80; x += 256) {
    int l = x >> 4, w = x & 15;
    kwS[x] = (l == 4 && w >= 12) ? 0ULL : keepw[(size_t)img * 80 + x];
  }
  __syncthreads();
  if (tid < 5) {
    int acc = 0;
    for (int w = 0; w < 16; ++w) { wp[tid][w] = acc; acc += (int)__popcll(kwS[tid * 16 + w]); }
    wp[tid][16] = acc;
  }
  __syncthreads();
  const unsigned long long* kp = keyP + (size_t)img * K_SEL;
  for (int i = tid; i < K_SEL; i += 256) {
    int l = (i < 4000) ? i / 1000 : 4;
    int li = i - l * 1000;
    unsigned long long wmask = kwS[l * 16 + (li >> 6)];
    if ((wmask >> (li & 63)) & 1ULL) {
      int j = wp[l][li >> 6] + (int)__popcll(wmask & ((1ULL << (li & 63)) - 1ULL));
      lkey[l * 1000 + j] = kp[i];
      lpos[l * 1000 + j] = i;
    }
  }
  __syncthreads();
  const float4* b4 = (const float4*)boxP + (size_t)img * K_SEL;
  float4* out4 = (float4*)out + (size_t)img * 1000;
  int kn = wp[lvl][16];
  for (int j = tid; j < kn; j += 256) {
    unsigned long long key = lkey[lvl * 1000 + j];
    int grank = j;
#pragma unroll
    for (int l2 = 0; l2 < 5; ++l2) {
      if (l2 == lvl) continue;
      int lo = 0, hi = wp[l2][16];
      const unsigned long long* a = &lkey[l2 * 1000];
      while (lo < hi) { int mid = (lo + hi) >> 1; if (a[mid] > key) lo = mid + 1; else hi = mid; }
      grank += lo;                            // count of keys > key in level l2
    }
    if (grank < 1000) out4[grank] = b4[lpos[lvl * 1000 + j]];
  }
  if (lvl == 0) {                             // pad region [KT,1000) has no grank: disjoint
    int KT = wp[0][16] + wp[1][16] + wp[2][16] + wp[3][16] + wp[4][16];
    for (int s = min(KT, 1000) + tid; s < 1000; s += 256)
      out4[s] = make_float4(0.f, 0.f, 0.f, 0.f);          // zero-pad tail
  }
}

extern "C" void kernel_launch(void* const* d_in, const int* in_sizes, int n_in,
                              void* d_out, int out_size, void* d_ws, size_t ws_size,
                              hipStream_t stream) {
  (void)in_sizes; (void)n_in;
  // setup_inputs() dict order is INTERLEAVED: obj_l0, delta_l0, obj_l1, delta_l1, ..., anchors
  P5 obj, del;
  for (int i = 0; i < 5; ++i) {
    obj.p[i] = (const float*)d_in[2 * i];
    del.p[i] = (const float*)d_in[2 * i + 1];
  }
  const float* anchors = (const float*)d_in[10];
  float* out = (float*)d_out;
  char* ws = (char*)d_ws;

  // ws layout (bytes)
  unsigned* cnt               = (unsigned*)(ws + 0);                   // 160
  int* Bthr                   = (int*)(ws + 192);                      // 160
  unsigned long long* candK   = (unsigned long long*)(ws + 512);       // 40*16384*8 = 5242880 -> 5243392
  unsigned* selSV             = (unsigned*)(ws + 5243392);             // 152576 -> 5395968
  unsigned* selIdx            = (unsigned*)(ws + 5395968);             // 152576 -> 5548544
  float* boxP                 = (float*)(ws + 5548544);                // 610304 -> 6158848
  unsigned long long* keyP    = (unsigned long long*)(ws + 6158848);   // 305152 -> 6464000
  unsigned long long* keepw   = (unsigned long long*)(ws + 6464000);   // 5120   -> 6469120
  unsigned long long* T       = (unsigned long long*)(ws + 6469120);   // 40*9216*8 = 2949120 -> 9418240
  unsigned* phist             = (unsigned*)(ws + 6469120);             // overlay on T (dead before k_lvlmask): 5242880 -> 11712000
  const size_t NEED = 11712000ULL;
  if (ws_size < NEED) { hipMemsetAsync(d_out, 0, (size_t)out_size * 4, stream); return; }

  k_hist    <<<dim3(8, 40), 256, 0, stream>>>(obj, phist);
  k_thresh  <<<40, 256, 0, stream>>>(phist, Bthr, cnt);
  k_gather  <<<dim3(32, 40), 256, 0, stream>>>(obj, Bthr, cnt, candK);
  k_select  <<<dim3(64, 40), 256, 0, stream>>>(cnt, candK, selSV, selIdx);
  k_decode  <<<dim3(19, 8), 256, 0, stream>>>(del, anchors, selSV, selIdx, boxP, keyP);
  k_lvlmask <<<dim3(622, 8), 64, 0, stream>>>(boxP, T);
  k_lvlnms  <<<40, 256, 0, stream>>>(keyP, T, keepw);
  k_merge   <<<40, 256, 0, stream>>>(keyP, boxP, keepw, out);
}

// Round 4
// 221.264 us; speedup vs baseline: 1.1351x; 1.1351x over previous
//
#include <hip/hip_runtime.h>
#include <cstdint>

#define K_SEL 4768
#define CAND_CAP 16384
#define NBIN 4096
#define BUFCAP 512
#define TPAD 9216   // padded-triangular T words per (img,lvl): 64 * sum((c+1)|1, c=0..15)

struct P5 { const float* p[5]; };

__device__ __forceinline__ unsigned fsortkey(float f) {
  unsigned b = __float_as_uint(f);
  return (b & 0x80000000u) ? ~b : (b | 0x80000000u);
}

// ------- histogram of sortable-logit top-12 bits per (img,lvl): per-block partials ------
__global__ __launch_bounds__(256) void k_hist(P5 obj, unsigned* phist) {
  int p = blockIdx.y; int img = p / 5, lvl = p % 5;
  int f = 256 >> lvl; int n = 3 * f * f;
  __shared__ unsigned lh[NBIN];
  for (int b = threadIdx.x; b < NBIN; b += 256) lh[b] = 0;
  __syncthreads();
  const float4* src4 = (const float4*)(obj.p[lvl] + (size_t)img * n);
  int n4 = n >> 2;
  int chunk = (n4 + gridDim.x - 1) / gridDim.x;
  int e0 = blockIdx.x * chunk, e1 = min(n4, e0 + chunk);
  for (int e = e0 + threadIdx.x; e < e1; e += 256) {
    float4 v = src4[e];
    atomicAdd(&lh[fsortkey(v.x) >> 20], 1u);
    atomicAdd(&lh[fsortkey(v.y) >> 20], 1u);
    atomicAdd(&lh[fsortkey(v.z) >> 20], 1u);
    atomicAdd(&lh[fsortkey(v.w) >> 20], 1u);
  }
  __syncthreads();
  unsigned* dst = phist + ((size_t)(p * 8 + blockIdx.x)) * NBIN;
  for (int b = threadIdx.x; b < NBIN; b += 256) dst[b] = lh[b];   // unconditional: no pre-zero
}

// ------- sum partials, find threshold bin B (count(bin >= B) >= kk), zero cnt ----------
__global__ __launch_bounds__(256) void k_thresh(const unsigned* phist, int* Bthr, unsigned* cnt) {
  int p = blockIdx.x; int lvl = p % 5;
  unsigned kk = (lvl == 4) ? 768u : 1000u;
  __shared__ unsigned hsum[NBIN];
  __shared__ unsigned csum[256];
  int c = threadIdx.x;
  unsigned tot[16];
#pragma unroll
  for (int k = 0; k < 16; ++k) tot[k] = 0;
  for (int g = 0; g < 8; ++g) {
    const unsigned* hp = phist + ((size_t)(p * 8 + g)) * NBIN + c * 16;
#pragma unroll
    for (int k = 0; k < 16; ++k) tot[k] += hp[k];
  }
  unsigned s = 0;
#pragma unroll
  for (int k = 0; k < 16; ++k) { hsum[c * 16 + k] = tot[k]; s += tot[k]; }
  csum[c] = s;
  __syncthreads();
  if (c == 0) {
    unsigned acc = 0; int B = 0;
    for (int cc = 255; cc >= 0; --cc) {
      if (acc + csum[cc] >= kk) {
        for (int b = 15; b >= 0; --b) {
          acc += hsum[cc * 16 + b];
          if (acc >= kk) { B = cc * 16 + b; break; }
        }
        break;
      }
      acc += csum[cc];
    }
    Bthr[p] = B;
    cnt[p] = 0;                              // replaces ws memset for gather's counter
  }
}

// ------- gather candidates (bin >= B): float4 reads, LDS-buffered, ONE atomic per block -
__global__ __launch_bounds__(256) void k_gather(P5 obj, const int* Bthr, unsigned* cnt,
                                                unsigned long long* ck) {
  int p = blockIdx.y; int img = p / 5, lvl = p % 5;
  int f = 256 >> lvl; int hw = f * f; int n = 3 * hw;
  int B = Bthr[p];
  int shift = 2 * (8 - lvl);
  const float4* src4 = (const float4*)(obj.p[lvl] + (size_t)img * n);
  int n4 = n >> 2;
  unsigned long long* dst = ck + (size_t)p * CAND_CAP;
  int tid = threadIdx.x;
  int lane = tid & 63, wv = tid >> 6;
  __shared__ unsigned long long buf[4][BUFCAP];
  __shared__ unsigned wTot[4];
  __shared__ unsigned blkBase;
  unsigned wc = 0;                             // wave-uniform running count
  for (int e = blockIdx.x * 256 + tid; e < n4; e += gridDim.x * 256) {
    float4 v = src4[e];
    float vv[4] = {v.x, v.y, v.z, v.w};
#pragma unroll
    for (int j = 0; j < 4; ++j) {
      unsigned sv = fsortkey(vv[j]);
      bool pass = (int)(sv >> 20) >= B;
      unsigned long long m = __ballot(pass);
      if (m) {
        if (pass) {
          unsigned pos = wc + (unsigned)__popcll(m & ((1ULL << lane) - 1ULL));
          int ee = e * 4 + j;
          int a = ee >> shift;                 // ee / hw
          int r = ee & (hw - 1);               // ee % hw
          unsigned kidx = (unsigned)(r * 3 + a); // reference flatten order (y*W+x)*A + a
          unsigned long long key = ((unsigned long long)sv << 32) | (0xFFFFFFFFu - kidx);
          if (pos < BUFCAP) buf[wv][pos] = key;
          else {                               // overflow safety (pathological skew only)
            unsigned gp = atomicAdd(&cnt[p], 1u);
            if (gp < CAND_CAP) dst[gp] = key;
          }
        }
        wc += (unsigned)__popcll(m);
      }
    }
  }
  if (lane == 0) wTot[wv] = min(wc, (unsigned)BUFCAP);
  __syncthreads();
  if (tid == 0) {
    unsigned tot = wTot[0] + wTot[1] + wTot[2] + wTot[3];
    blkBase = tot ? atomicAdd(&cnt[p], tot) : 0u;
  }
  __syncthreads();
  unsigned myOff = blkBase;
  for (int x = 0; x < wv; ++x) myOff += wTot[x];
  unsigned wn = wTot[wv];
  for (unsigned j = lane; j < wn; j += 64) {
    unsigned gp = myOff + j;
    if (gp < CAND_CAP) dst[gp] = buf[wv][j];   // coalesced flush
  }
}

// ------- exact top-kk per level by rank counting, LDS-staged keys ----------------------
__global__ __launch_bounds__(256) void k_select(const unsigned* cnt, const unsigned long long* ck,
                                                unsigned* selSV, unsigned* selIdx) {
  int p = blockIdx.y; int img = p / 5, lvl = p % 5;
  int Cc = min((int)cnt[p], CAND_CAP);
  if (blockIdx.x * 256 >= Cc) return;
  int kk = (lvl == 4) ? 768 : 1000;
  int soff = lvl * 1000;
  const unsigned long long* keys = ck + (size_t)p * CAND_CAP;
  __shared__ unsigned long long sk[4096];
  int stage = min(Cc, 4096);
  for (int j = threadIdx.x; j < stage; j += 256) sk[j] = keys[j];
  __syncthreads();
  int c = blockIdx.x * 256 + threadIdx.x;
  if (c >= Cc) return;
  unsigned long long kc = keys[c];
  int rank = 0;
#pragma unroll 8
  for (int j = 0; j < stage; ++j) rank += (sk[j] > kc) ? 1 : 0;
  for (int j = stage; j < Cc; ++j) rank += (keys[j] > kc) ? 1 : 0;
  if (rank < kk) {
    int slot = img * K_SEL + soff + rank;
    selSV[slot]  = (unsigned)(kc >> 32);
    selIdx[slot] = 0xFFFFFFFFu - (unsigned)kc;
  }
}

// ---------------- decode + clip + validity for the 4768 selected per image --------------
__global__ __launch_bounds__(256) void k_decode(P5 del, const float* anchors,
                                                const unsigned* selSV, const unsigned* selIdx,
                                                float* boxP, unsigned long long* keyP) {
  int i = blockIdx.x * 256 + threadIdx.x;
  if (i >= K_SEL) return;
  int img = blockIdx.y;
  int lvl = (i < 4000) ? (i / 1000) : 4;
  int f = 256 >> lvl, hw = f * f;
  const int aoffA[5] = {0, 196608, 245760, 258048, 261120};
  int slot = img * K_SEL + i;
  unsigned k = selIdx[slot];
  unsigned sv = selSV[slot];
  int a = (int)(k % 3u); int r = (int)(k / 3u);
  int y = r >> (8 - lvl); int x = r & (f - 1);
  const float* dp = del.p[lvl] + (size_t)(img * 12 + a * 4) * hw + (size_t)y * f + x;
  float d0 = dp[0], d1 = dp[hw], d2 = dp[2 * hw], d3 = dp[3 * hw];
  const float* ar = anchors + (size_t)(aoffA[lvl] + (int)k) * 4;
  float a0 = ar[0], a1 = ar[1], a2 = ar[2], a3 = ar[3];
  // numpy-faithful, no FMA contraction
  float w = __fsub_rn(a2, a0), h = __fsub_rn(a3, a1);
  float cx = __fadd_rn(a0, __fmul_rn(0.5f, w));
  float cy = __fadd_rn(a1, __fmul_rn(0.5f, h));
  const float CLIP = 4.135166556742356f;     // log(1000/16)
  float dw = fminf(d2, CLIP), dh = fminf(d3, CLIP);
  float pcx = __fadd_rn(__fmul_rn(d0, w), cx);
  float pcy = __fadd_rn(__fmul_rn(d1, h), cy);
  float pw = __fmul_rn(expf(dw), w);
  float ph = __fmul_rn(expf(dh), h);
  float x1 = __fsub_rn(pcx, __fmul_rn(0.5f, pw));
  float y1 = __fsub_rn(pcy, __fmul_rn(0.5f, ph));
  float x2 = __fadd_rn(pcx, __fmul_rn(0.5f, pw));
  float y2 = __fadd_rn(pcy, __fmul_rn(0.5f, ph));
  float x1c = fminf(fmaxf(x1, 0.0f), 1024.0f);
  float y1c = fminf(fmaxf(y1, 0.0f), 1024.0f);
  float x2c = fminf(fmaxf(x2, 0.0f), 1024.0f);
  float y2c = fminf(fmaxf(y2, 0.0f), 1024.0f);
  bool valid = (__fsub_rn(x2c, x1c) >= 1e-3f) && (__fsub_rn(y2c, y1c) >= 1e-3f);
  float* bp = boxP + (size_t)slot * 4;
  bp[0] = x1c; bp[1] = y1c; bp[2] = x2c; bp[3] = y2c;
  unsigned low = 0xFFFFFFFFu - (unsigned)i;   // pos asc tie-break, unique keys
  keyP[slot] = valid ? (((unsigned long long)sv << 32) | low) : (unsigned long long)low;
}

// ---------------- IoU on offset boxes, bitwise matching reference -----------------------
__device__ __forceinline__ bool iou_gt(float rx1, float ry1, float rx2, float ry2, float rar,
                                       float cx1, float cy1, float cx2, float cy2, float car) {
  float ltx = fmaxf(rx1, cx1), lty = fmaxf(ry1, cy1);
  float rbx = fminf(rx2, cx2), rby = fminf(ry2, cy2);
  float wx = fmaxf(__fsub_rn(rbx, ltx), 0.0f);
  float wy = fmaxf(__fsub_rn(rby, lty), 0.0f);
  float inter = __fmul_rn(wx, wy);
  float denom = __fadd_rn(__fsub_rn(__fadd_rn(rar, car), inter), 1e-9f);
  return __fdiv_rn(inter, denom) > 0.7f;
}

// ---- TRANSPOSED suppression mask T[i] = "which j<i suppress i", triangular-packed ------
// Role-swap vs row-major version: ROW boxes staged in LDS, COLUMN box in registers ->
// each thread directly accumulates the suppressor word of its column box; no transpose
// step. IoU is bitwise symmetric (fmax/fmin/fsub/fmul/fadd/fdiv identical both ways).
// Packing: row i (chunk ci=i>>6) holds words w=0..ci at T[64*Pt[ci] + (i&63)*sc + w],
// sc=(ci+1)|1 (odd stride -> <=4-way LDS bank conflict when k_lvlnms reads it).
__global__ __launch_bounds__(64) void k_lvlmask(const float* boxP, unsigned long long* T) {
  int img = blockIdx.y;
  int q = blockIdx.x;                        // 0..621 per image
  int lvl, q2;
  if (q < 544) { lvl = q / 136; q2 = q - lvl * 136; }
  else         { lvl = 4;       q2 = q - 544; }
  int kk = (lvl == 4) ? 768 : 1000;
  int nch = (kk + 63) >> 6;
  int rb = 0;
  while (q2 >= nch - rb) { q2 -= nch - rb; ++rb; }    // upper-tri (rb, cb>=rb)
  int cb = rb + q2;
  int t = threadIdx.x;
  float off = __fmul_rn((float)lvl, 1025.0f);
  const float4* b4 = (const float4*)boxP + (size_t)img * K_SEL + lvl * 1000;
  __shared__ float rx1s[64], ry1s[64], rx2s[64], ry2s[64], rars[64];
  int j = rb * 64 + t;                       // ROW box staged in LDS
  if (j < kk) {
    float4 bb = b4[j];
    float ox1 = __fadd_rn(bb.x, off), oy1 = __fadd_rn(bb.y, off);
    float ox2 = __fadd_rn(bb.z, off), oy2 = __fadd_rn(bb.w, off);
    rx1s[t] = ox1; ry1s[t] = oy1; rx2s[t] = ox2; ry2s[t] = oy2;
    rars[t] = __fmul_rn(__fsub_rn(ox2, ox1), __fsub_rn(oy2, oy1));
  }
  __syncthreads();
  int i = cb * 64 + t;                       // COLUMN box in registers
  if (i >= kk) return;
  float4 bb = b4[i];
  float cx1 = __fadd_rn(bb.x, off), cy1 = __fadd_rn(bb.y, off);
  float cx2 = __fadd_rn(bb.z, off), cy2 = __fadd_rn(bb.w, off);
  float car = __fmul_rn(__fsub_rn(cx2, cx1), __fsub_rn(cy2, cy1));
  int jmaxR = min(64, kk - rb * 64);
  int jend = (rb == cb) ? min(t, jmaxR) : jmaxR;      // diag: only rows jj < t
  unsigned long long bits = 0;
  for (int jj = 0; jj < jend; ++jj) {
    if (iou_gt(rx1s[jj], ry1s[jj], rx2s[jj], ry2s[jj], rars[jj], cx1, cy1, cx2, cy2, car))
      bits |= (1ULL << jj);
  }
  const int Pt[16] = {0, 1, 4, 7, 12, 17, 24, 31, 40, 49, 60, 71, 84, 97, 112, 127};
  int sc = (cb + 1) | 1;
  T[(size_t)(img * 5 + lvl) * TPAD + 64 * Pt[cb] + t * sc + rb] = bits;
}

// ---- per-level greedy NMS: LDS-staged T + single-wave serial chunk sweep ---------------
// Chunk c handled by 64 lanes with EXACT prefix info (keep-words kw[0..c-1] from earlier
// chunks, wave-uniform via ballot). dead0 = OR_w(T[i][w] & kw[w]); within-chunk 2-4-round
// ballot fixpoint on the diagonal word (proven in r2). All 16 T-words read as one batch
// of independent ds_read_b64 (one lgkm wait); kw[] fully unrolled (no dynamic reg index).
__global__ __launch_bounds__(256) void k_lvlnms(const unsigned long long* keyP,
                                                const unsigned long long* Tg_,
                                                unsigned long long* keepw) {
  int p = blockIdx.x; int img = p / 5, lvl = p % 5;
  int kk = (lvl == 4) ? 768 : 1000;
  int tw = (lvl == 4) ? 5376 : TPAD;         // words used (lvl4: chunks 0..11 only)
  int tid = threadIdx.x;
  __shared__ __align__(16) unsigned long long Ts[TPAD];   // 72 KiB
  const unsigned long long* Tg = Tg_ + (size_t)p * TPAD;
  const unsigned long long* kp = keyP + (size_t)img * K_SEL + lvl * 1000;
  // wave0: prefetch validity bits for all 16 chunks (overlaps the staging loop's loads)
  unsigned vmask = 0;
  if (tid < 64) {
#pragma unroll
    for (int c = 0; c < 16; ++c) {
      int i = c * 64 + tid;
      bool v = (i < kk) && ((kp[min(i, kk - 1)] >> 32) != 0ULL);
      vmask |= v ? (1u << c) : 0u;
    }
  }
  for (int x = tid; x < (tw >> 1); x += 256)
    ((ulonglong2*)Ts)[x] = ((const ulonglong2*)Tg)[x];    // coalesced 16B staging
  __syncthreads();
  if (tid >= 64) return;                     // waves 1-3 done (no further barriers)
  int t = tid;
  const int Pt[16] = {0, 1, 4, 7, 12, 17, 24, 31, 40, 49, 60, 71, 84, 97, 112, 127};
  unsigned long long kw[16];
#pragma unroll
  for (int w = 0; w < 16; ++w) kw[w] = 0ULL;
#pragma unroll
  for (int c = 0; c < 16; ++c) {
    if (c * 64 < kk) {
      int base = 64 * Pt[c] + t * ((c + 1) | 1);
      unsigned long long tv[16];
#pragma unroll
      for (int w = 0; w < 16; ++w) tv[w] = Ts[base + w]; // batch reads; w>c garbage, masked
      unsigned long long a = 0;
#pragma unroll
      for (int w = 0; w < 16; ++w) a |= tv[w] & kw[w];   // kw[w]=0 for w>=c
      unsigned long long colT = tv[c];                   // diag word: suppressors j<t in chunk
      bool alive = ((vmask >> c) & 1u) && (a == 0ULL);
      unsigned long long keepm = 0ULL;
      unsigned long long actm = __ballot(alive);
      while (actm) {
        bool cank = alive && ((colT & actm) == 0ULL);    // no alive suppressor below t
        unsigned long long newk = __ballot(cank);
        keepm |= newk;
        alive = alive && !cank && ((colT & newk) == 0ULL);
        actm = __ballot(alive);
      }
      kw[c] = keepm;                                     // static index (unrolled)
    }
  }
  if (t == 0) {
#pragma unroll
    for (int c = 0; c < 16; ++c) keepw[(size_t)p * 16 + c] = kw[c];  // uniform ballot values
  }
}

// ---- merge: exact global rank of each kept box via per-level compaction + 4 binary
// ---- searches. 40 blocks = (img,lvl): each block compacts ALL levels (cheap, coalesced)
// ---- but ranks only its own level's kept entries -> 5x less serial LDS-chain latency.
// ---- granks biject onto 0..KT-1 so cross-block writes never collide; pad is disjoint.
__global__ __launch_bounds__(256) void k_merge(const unsigned long long* keyP, const float* boxP,
                                               const unsigned long long* keepw, float* out) {
  int p = blockIdx.x; int img = p / 5, lvl = p % 5;
  int tid = threadIdx.x;
  __shared__ unsigned long long lkey[5000];   // level l at l*1000: compacted kept keys (desc)
  __shared__ int lpos[5000];                  // original within-image slot
  __shared__ int wp[5][17];                   // per-level word-prefix popcounts
  __shared__ unsigned long long kwS[80];
  for (int x = tid; x < 80; x += 256) {
    kwS[x] = keepw[(size_t)img * 80 + x];     // all 16 words now written by k_lvlnms
  }
  __syncthreads();
  if (tid < 5) {
    int acc = 0;
    for (int w = 0; w < 16; ++w) { wp[tid][w] = acc; acc += (int)__popcll(kwS[tid * 16 + w]); }
    wp[tid][16] = acc;
  }
  __syncthreads();
  const unsigned long long* kp = keyP + (size_t)img * K_SEL;
  for (int i = tid; i < K_SEL; i += 256) {
    int l = (i < 4000) ? i / 1000 : 4;
    int li = i - l * 1000;
    unsigned long long wmask = kwS[l * 16 + (li >> 6)];
    if ((wmask >> (li & 63)) & 1ULL) {
      int j = wp[l][li >> 6] + (int)__popcll(wmask & ((1ULL << (li & 63)) - 1ULL));
      lkey[l * 1000 + j] = kp[i];
      lpos[l * 1000 + j] = i;
    }
  }
  __syncthreads();
  const float4* b4 = (const float4*)boxP + (size_t)img * K_SEL;
  float4* out4 = (float4*)out + (size_t)img * 1000;
  int kn = wp[lvl][16];
  for (int j = tid; j < kn; j += 256) {
    unsigned long long key = lkey[lvl * 1000 + j];
    int grank = j;
#pragma unroll
    for (int l2 = 0; l2 < 5; ++l2) {
      if (l2 == lvl) continue;
      int lo = 0, hi = wp[l2][16];
      const unsigned long long* a = &lkey[l2 * 1000];
      while (lo < hi) { int mid = (lo + hi) >> 1; if (a[mid] > key) lo = mid + 1; else hi = mid; }
      grank += lo;                            // count of keys > key in level l2
    }
    if (grank < 1000) out4[grank] = b4[lpos[lvl * 1000 + j]];
  }
  if (lvl == 0) {                             // pad region [KT,1000) has no grank: disjoint
    int KT = wp[0][16] + wp[1][16] + wp[2][16] + wp[3][16] + wp[4][16];
    for (int s = min(KT, 1000) + tid; s < 1000; s += 256)
      out4[s] = make_float4(0.f, 0.f, 0.f, 0.f);          // zero-pad tail
  }
}

extern "C" void kernel_launch(void* const* d_in, const int* in_sizes, int n_in,
                              void* d_out, int out_size, void* d_ws, size_t ws_size,
                              hipStream_t stream) {
  (void)in_sizes; (void)n_in;
  // setup_inputs() dict order is INTERLEAVED: obj_l0, delta_l0, obj_l1, delta_l1, ..., anchors
  P5 obj, del;
  for (int i = 0; i < 5; ++i) {
    obj.p[i] = (const float*)d_in[2 * i];
    del.p[i] = (const float*)d_in[2 * i + 1];
  }
  const float* anchors = (const float*)d_in[10];
  float* out = (float*)d_out;
  char* ws = (char*)d_ws;

  // ws layout (bytes)
  unsigned* cnt               = (unsigned*)(ws + 0);                   // 160
  int* Bthr                   = (int*)(ws + 192);                      // 160
  unsigned long long* candK   = (unsigned long long*)(ws + 512);       // 40*16384*8 = 5242880 -> 5243392
  unsigned* selSV             = (unsigned*)(ws + 5243392);             // 152576 -> 5395968
  unsigned* selIdx            = (unsigned*)(ws + 5395968);             // 152576 -> 5548544
  float* boxP                 = (float*)(ws + 5548544);                // 610304 -> 6158848
  unsigned long long* keyP    = (unsigned long long*)(ws + 6158848);   // 305152 -> 6464000
  unsigned long long* keepw   = (unsigned long long*)(ws + 6464000);   // 5120   -> 6469120
  unsigned long long* T       = (unsigned long long*)(ws + 6469120);   // 40*9216*8 = 2949120 -> 9418240
  unsigned* phist             = (unsigned*)(ws + 6469120);             // overlay on T (dead before k_lvlmask): 5242880 -> 11712000
  const size_t NEED = 11712000ULL;
  if (ws_size < NEED) { hipMemsetAsync(d_out, 0, (size_t)out_size * 4, stream); return; }

  k_hist    <<<dim3(8, 40), 256, 0, stream>>>(obj, phist);
  k_thresh  <<<40, 256, 0, stream>>>(phist, Bthr, cnt);
  k_gather  <<<dim3(32, 40), 256, 0, stream>>>(obj, Bthr, cnt, candK);
  k_select  <<<dim3(64, 40), 256, 0, stream>>>(cnt, candK, selSV, selIdx);
  k_decode  <<<dim3(19, 8), 256, 0, stream>>>(del, anchors, selSV, selIdx, boxP, keyP);
  k_lvlmask <<<dim3(622, 8), 64, 0, stream>>>(boxP, T);
  k_lvlnms  <<<40, 256, 0, stream>>>(keyP, T, keepw);
  k_merge   <<<40, 256, 0, stream>>>(keyP, boxP, keepw, out);
}